// Round 13
// baseline (200.197 us; speedup 1.0000x reference)
//
#include <hip/hip_runtime.h>
#include <math.h>

#define DECAY 0.8f
constexpr int B_     = 16;
constexpr int NSEQ   = 4096;
constexpr int D      = 64;
constexpr int C      = 4096;
constexpr int N      = B_ * NSEQ;       // 65536 rows
constexpr int NCHUNK = 4;               // code chunks (blockIdx.y)
constexpr int CCHUNK = C / NCHUNK;      // 1024 codes
constexpr int PANEL  = 128;             // codes per panel (32 KB LDS)
constexpr int NPANEL = CCHUNK / PANEL;  // 8
constexpr int TILE_ELEMS = 32 * D;      // 2048 elems per 32-code tile image

#define GATE_THR  3e-4f                  // >> 2x mfma-split err (~1e-4 at ||x||<=12)
#define CONS_THR  1e-3f                  // consistency: exact-vs-approx winner

typedef __attribute__((ext_vector_type(8)))  short bf16x8;
typedef __attribute__((ext_vector_type(16))) float f32x16;

__device__ __forceinline__ unsigned short bf16_rn(float f) {
    unsigned u = __builtin_bit_cast(unsigned, f);
    u += 0x7FFFu + ((u >> 16) & 1u);
    return (unsigned short)(u >> 16);
}
__device__ __forceinline__ float bf16_to_f(unsigned short h) {
    unsigned u = ((unsigned)h) << 16;
    return __builtin_bit_cast(float, u);
}
__device__ __forceinline__ f32x16 mfma32(bf16x8 a, bf16x8 b, f32x16 c) {
    return __builtin_amdgcn_mfma_f32_32x32x16_bf16(a, b, c, 0, 0, 0);
}
__device__ __forceinline__ void gload_lds16(const unsigned short* g,
                                            unsigned short* l) {
    __builtin_amdgcn_global_load_lds(
        (const __attribute__((address_space(1))) unsigned int*)g,
        (__attribute__((address_space(3))) unsigned int*)l, 16, 0, 0);
}

// ---------------------------------------------------------------------------
// Kernel 1: embed_n = l2norm(embed) (f32), bf16 hi/lo split in the
// TRANSPOSED-GRANULE tile image (t*2048 + (g*32+r)*8 + e). Zeroes
// cnt / dirty_count.
// ---------------------------------------------------------------------------
__global__ __launch_bounds__(256) void prep_e_kernel(
    const float* __restrict__ embed,
    float* __restrict__ embed_n,
    unsigned short* __restrict__ e_hi,
    unsigned short* __restrict__ e_lo,
    int* __restrict__ cnt,
    int* __restrict__ dirty_count)
{
    int code = blockIdx.x * 4 + (threadIdx.x >> 6);
    int lane = threadIdx.x & 63;
    float v = embed[code * D + lane];
    float ss = v * v;
    #pragma unroll
    for (int o = 32; o > 0; o >>= 1) ss += __shfl_xor(ss, o);
    float inv = 1.0f / fmaxf(sqrtf(ss), 1e-12f);
    float en = v * inv;
    embed_n[code * D + lane] = en;

    unsigned short hi = bf16_rn(en);
    unsigned short lo = bf16_rn(en - bf16_to_f(hi));
    int t = code >> 5, r = code & 31;
    int g = lane >> 3, e = lane & 7;
    size_t pos = (size_t)t * TILE_ELEMS + (g * 32 + r) * 8 + e;
    e_hi[pos] = hi;
    e_lo[pos] = lo;

    if (lane == 0) cnt[code] = 0;
    if (blockIdx.x == 0 && threadIdx.x == 0) *dirty_count = 0;
}

// ---------------------------------------------------------------------------
// Kernel 2: MFMA partial argmax over a 1024-code chunk (blockIdx.y of 4).
// 512-thread blocks (8 waves share each staged panel); 1024 blocks =
// 4 blocks/CU x 8 waves = 32 waves/CU; PANEL=128 codes (32 KB LDS,
// 128 KB/CU at 4 blocks) -> 8 panel generations per chunk (half round-12's
// barrier count). Two independent 6-MFMA chains; half-tile (16-code) top-2
// bookkeeping, hi-halves merged by one shfl_xor(32); conservative m2x.
// Partial (m1, ht, m2x, 0) -> the row's quantize slot (float4 at chunk*4).
// ---------------------------------------------------------------------------
__global__ __launch_bounds__(512) void assign_mfma_kernel(
    const float* __restrict__ x,
    const unsigned short* __restrict__ e_hi,
    const unsigned short* __restrict__ e_lo,
    float* __restrict__ part)               // == q_out region of d_out
{
    __shared__ unsigned short lds_hi[4 * TILE_ELEMS];   // 16 KB
    __shared__ unsigned short lds_lo[4 * TILE_ELEMS];   // 16 KB

    const int tid  = threadIdx.x;
    const int lane = tid & 63;
    const int wid  = tid >> 6;                   // 0..7
    const int m    = lane & 31;
    const int hi   = lane >> 5;                  // 0/1
    const int rb   = (blockIdx.x * 8 + wid) * 32;
    const int cy   = blockIdx.y;                 // code chunk 0..3

    // ---- x fragments: 4 K-chunks of 16, bf16 hi/lo split
    bf16x8 xhi[4], xlo[4];
    #pragma unroll
    for (int c = 0; c < 4; ++c) {
        const float* p = x + (size_t)(rb + m) * D + c * 16 + hi * 8;
        float4 t0 = *(const float4*)p;
        float4 t1 = *(const float4*)(p + 4);
        float e[8] = {t0.x, t0.y, t0.z, t0.w, t1.x, t1.y, t1.z, t1.w};
        bf16x8 h, l2;
        #pragma unroll
        for (int j = 0; j < 8; ++j) {
            unsigned short hh = bf16_rn(e[j]);
            h[j]  = (short)hh;
            l2[j] = (short)bf16_rn(e[j] - bf16_to_f(hh));
        }
        xhi[c] = h;
        xlo[c] = l2;
    }

    float m1 = -3.4e38f, m2 = -3.4e38f;
    int   tl = 0;

    for (int p = 0; p < NPANEL; ++p) {           // 8 panels of 128 codes
        const size_t pbase = ((size_t)cy * NPANEL + p) * (4 * TILE_ELEMS);
        __syncthreads();
        // linear stage: 8192 elems/array, 512 thr -> 2 gloads per array
        gload_lds16(e_hi + pbase + tid * 8,        &lds_hi[tid * 8]);
        gload_lds16(e_hi + pbase + 4096 + tid * 8, &lds_hi[4096 + tid * 8]);
        gload_lds16(e_lo + pbase + tid * 8,        &lds_lo[tid * 8]);
        gload_lds16(e_lo + pbase + 4096 + tid * 8, &lds_lo[4096 + tid * 8]);
        __syncthreads();

        #pragma unroll
        for (int t = 0; t < 4; ++t) {            // 4 code-tiles of 32
            const int pt = (cy * NPANEL + p) * 4 + t;    // tile id 0..127
            f32x16 accA = {}, accB = {};         // two independent chains
            #pragma unroll
            for (int c = 0; c < 2; ++c) {
                const int off = t * TILE_ELEMS + ((c * 2 + hi) * 32 + m) * 8;
                bf16x8 eh = *(const bf16x8*)(lds_hi + off);
                bf16x8 el = *(const bf16x8*)(lds_lo + off);
                accA = mfma32(eh, xhi[c], accA);
                accA = mfma32(el, xhi[c], accA);
                accA = mfma32(eh, xlo[c], accA);
            }
            #pragma unroll
            for (int c = 2; c < 4; ++c) {
                const int off = t * TILE_ELEMS + ((c * 2 + hi) * 32 + m) * 8;
                bf16x8 eh = *(const bf16x8*)(lds_hi + off);
                bf16x8 el = *(const bf16x8*)(lds_lo + off);
                accB = mfma32(eh, xhi[c], accB);
                accB = mfma32(el, xhi[c], accB);
                accB = mfma32(eh, xlo[c], accB);
            }
            // per half-tile: sum chains + 8-max tree + top-2 update
            #pragma unroll
            for (int h = 0; h < 2; ++h) {
                float s0 = accA[h*8+0] + accB[h*8+0];
                float s1 = accA[h*8+1] + accB[h*8+1];
                float s2 = accA[h*8+2] + accB[h*8+2];
                float s3 = accA[h*8+3] + accB[h*8+3];
                float s4 = accA[h*8+4] + accB[h*8+4];
                float s5 = accA[h*8+5] + accB[h*8+5];
                float s6 = accA[h*8+6] + accB[h*8+6];
                float s7 = accA[h*8+7] + accB[h*8+7];
                float tm = fmaxf(fmaxf(fmaxf(s0, s1), fmaxf(s2, s3)),
                                 fmaxf(fmaxf(s4, s5), fmaxf(s6, s7)));
                const int ht = pt * 2 + h;       // half-tile id 0..255
                float mn = fminf(m1, tm);
                bool  gt = tm > m1;
                tl = gt ? ht : tl;               // wave-uniform source
                m1 = fmaxf(m1, tm);
                m2 = fmaxf(m2, mn);
            }
        }
    }

    // ---- merge the two hi-halves (disjoint code subsets of the same row)
    {
        float b1 = __shfl_xor(m1, 32);
        float b2 = __shfl_xor(m2, 32);
        int   bt = __shfl_xor(tl, 32);
        float nm2 = fmaxf(fmaxf(m2, b2), fminf(m1, b1));
        bool  take = (b1 > m1);                  // exact ties -> m2==m1 -> dirty
        m1 = take ? b1 : m1;
        tl = take ? bt : tl;
        m2 = nm2;
    }
    if (lane < 32) {
        int row = rb + lane;
        float4 pr;
        pr.x = m1; pr.y = (float)tl; pr.z = m2; pr.w = 0.0f;
        *reinterpret_cast<float4*>(part + (size_t)row * D + cy * 4) = pr;
    }
}

// ---------------------------------------------------------------------------
// Kernel 3: merge + exact 16-code half-tile rescan + light scatter, one
// WAVE/row. Clean rows: ind + q gather + ONE int atomic (cnt[code]++ whose
// old value is the row's slot, saved to slot_arr) — replaces the 64 fp32
// atomics/row (16.7M -> 131k total; atomic THROUGHPUT was merge_scatter's
// floor, which privatization couldn't touch). Dirty rows -> fallback.
// ---------------------------------------------------------------------------
__global__ __launch_bounds__(256) void merge_rescan_kernel(
    const float* __restrict__ x,
    const float* __restrict__ embed,
    const float* __restrict__ embed_n,
    float* __restrict__ q_out,               // holds partials on entry
    float* __restrict__ ind_out,
    int* __restrict__ cnt,
    int* __restrict__ slot_arr,
    int* __restrict__ dirty_count,
    int* __restrict__ dirty_list)
{
    int wid  = threadIdx.x >> 6;
    int lane = threadIdx.x & 63;
    int row  = blockIdx.x * 4 + wid;

    // ---- merge the 4 chunk partials (broadcast reads)
    float w1a, m2x; int wt;
    {
        const float4* pp = reinterpret_cast<const float4*>(q_out + (size_t)row * D);
        float4 P = pp[0];
        w1a = P.x; wt = (int)P.y; m2x = P.z;
        #pragma unroll
        for (int j = 1; j < NCHUNK; ++j) {
            float4 Q = pp[j];
            float nm2 = fmaxf(fmaxf(m2x, Q.z), fminf(w1a, Q.x));
            if (Q.x > w1a) { w1a = Q.x; wt = (int)Q.y; }
            m2x = nm2;
        }
    }

    // ---- exact fp32 rescan of the 16-code winner half-tile
    int   csub = lane >> 2;                  // code within half-tile 0..15
    int   code = wt * 16 + csub;
    float dot;
    {
        const float4* ep = (const float4*)(embed_n + (size_t)code * D + (lane & 3) * 16);
        const float4* xp = (const float4*)(x + (size_t)row * D + (lane & 3) * 16);
        float a0 = 0.f, a1 = 0.f, a2 = 0.f, a3 = 0.f;
        #pragma unroll
        for (int k = 0; k < 4; ++k) {
            float4 e = ep[k], xx = xp[k];
            a0 = fmaf(e.x, xx.x, a0);
            a1 = fmaf(e.y, xx.y, a1);
            a2 = fmaf(e.z, xx.z, a2);
            a3 = fmaf(e.w, xx.w, a3);
        }
        dot = (a0 + a1) + (a2 + a3);
        dot += __shfl_xor(dot, 1);
        dot += __shfl_xor(dot, 2);           // all 4 lanes of group hold full dot
    }
    // butterfly top-2 over the 16 distinct codes
    float v = dot, s = -3.4e38f;
    int   vi = code;
    #pragma unroll
    for (int d = 4; d <= 32; d <<= 1) {
        float bv = __shfl_xor(v, d);
        float bs = __shfl_xor(s, d);
        int   bi = __shfl_xor(vi, d);
        float ns = fmaxf(fmaxf(s, bs), fminf(v, bv));
        bool  take = (bv > v) || (bv == v && bi < vi);
        v  = take ? bv : v;
        vi = take ? bi : vi;
        s  = ns;
    }

    bool dirty = (v - m2x <= GATE_THR) || (fabsf(v - w1a) > CONS_THR);
    if (dirty) {
        if (lane == 0) {
            int slot = atomicAdd(dirty_count, 1);
            dirty_list[slot] = row;
        }
        return;
    }

    // ---- light scatter (clean row)
    if (lane == 0) {
        ind_out[row] = (float)vi;
        slot_arr[row] = atomicAdd(&cnt[vi], 1);
    }
    q_out[(size_t)row * D + lane] = embed[(size_t)vi * D + lane];
}

// ---------------------------------------------------------------------------
// Kernel 4: exact fp32 re-argmax for dirty rows + their light scatter.
// ---------------------------------------------------------------------------
__global__ __launch_bounds__(256) void fallback_kernel(
    const float* __restrict__ x,
    const float* __restrict__ embed,
    const float* __restrict__ embed_n,
    const int* __restrict__ dirty_count,
    const int* __restrict__ dirty_list,
    float* __restrict__ ind_out,
    float* __restrict__ q_out,
    int* __restrict__ cnt,
    int* __restrict__ slot_arr)
{
    __shared__ float xs[D];
    __shared__ float bv[256];
    __shared__ int   bidx[256];
    int n_d = *dirty_count;
    for (int i = blockIdx.x; i < n_d; i += gridDim.x) {
        int row = dirty_list[i];
        __syncthreads();
        if (threadIdx.x < D) xs[threadIdx.x] = x[(size_t)row * D + threadIdx.x];
        __syncthreads();
        float best = -3.4e38f;
        int   bi   = 0;
        int   c0   = threadIdx.x * 16;
        for (int c = c0; c < c0 + 16; ++c) {
            const float4* ep = (const float4*)(embed_n + (size_t)c * D);
            const float4* xp = (const float4*)xs;
            float a0 = 0.f, a1 = 0.f, a2 = 0.f, a3 = 0.f;
            #pragma unroll
            for (int k = 0; k < D / 4; ++k) {
                float4 e = ep[k], xx = xp[k];
                a0 = fmaf(e.x, xx.x, a0);
                a1 = fmaf(e.y, xx.y, a1);
                a2 = fmaf(e.z, xx.z, a2);
                a3 = fmaf(e.w, xx.w, a3);
            }
            float dd = (a0 + a1) + (a2 + a3);
            if (dd > best) { best = dd; bi = c; }
        }
        bv[threadIdx.x]   = best;
        bidx[threadIdx.x] = bi;
        __syncthreads();
        #pragma unroll
        for (int s = 128; s > 0; s >>= 1) {
            if (threadIdx.x < s) {
                float v2 = bv[threadIdx.x + s];
                int   i2 = bidx[threadIdx.x + s];
                if (v2 > bv[threadIdx.x] ||
                    (v2 == bv[threadIdx.x] && i2 < bidx[threadIdx.x])) {
                    bv[threadIdx.x]   = v2;
                    bidx[threadIdx.x] = i2;
                }
            }
            __syncthreads();
        }
        int fi = bidx[0];
        if (threadIdx.x == 0) {
            ind_out[row] = (float)fi;
            slot_arr[row] = atomicAdd(&cnt[fi], 1);
        }
        if (threadIdx.x < 64)
            q_out[(size_t)row * D + threadIdx.x] =
                embed[(size_t)fi * D + threadIdx.x];
        __syncthreads();
    }
}

// ---------------------------------------------------------------------------
// Kernel 5: exclusive prefix sum over the 4096 code counts. One block.
// ---------------------------------------------------------------------------
__global__ __launch_bounds__(256) void scan_kernel(
    const int* __restrict__ cnt,
    int* __restrict__ offset)
{
    __shared__ int pre[256];
    int base = threadIdx.x * 16;
    int local[16];
    int s = 0;
    #pragma unroll
    for (int i = 0; i < 16; ++i) { local[i] = s; s += cnt[base + i]; }
    pre[threadIdx.x] = s;
    __syncthreads();
    if (threadIdx.x == 0) {
        int a = 0;
        for (int j = 0; j < 256; ++j) { int t = pre[j]; pre[j] = a; a += t; }
    }
    __syncthreads();
    int p = pre[threadIdx.x];
    #pragma unroll
    for (int i = 0; i < 16; ++i) offset[base + i] = p + local[i];
}

// ---------------------------------------------------------------------------
// Kernel 6: scatter rows into code-sorted order (atomic-free).
// ---------------------------------------------------------------------------
__global__ __launch_bounds__(256) void scatter_rows_kernel(
    const float* __restrict__ ind_out,
    const int* __restrict__ slot_arr,
    const int* __restrict__ offset,
    int* __restrict__ sorted)
{
    int row  = blockIdx.x * 256 + threadIdx.x;
    int code = (int)ind_out[row];
    sorted[offset[code] + slot_arr[row]] = row;
}

// ---------------------------------------------------------------------------
// Kernel 7: segmented sum + EMA finalize, one WAVE per code. Walks the
// code's sorted rows (uniform list address -> scalar loads), accumulates
// x/||x|| (norm via full-wave shfl reduce), then l2norm + EMA.
// ---------------------------------------------------------------------------
__global__ __launch_bounds__(256) void sumfin_kernel(
    const float* __restrict__ x,
    const float* __restrict__ embed,
    const float* __restrict__ cluster_size,
    const float* __restrict__ embed_n,
    const int* __restrict__ cnt,
    const int* __restrict__ offset,
    const int* __restrict__ sorted,
    float* __restrict__ new_embed_out,
    float* __restrict__ new_cs_out)
{
    int code = blockIdx.x * 4 + (threadIdx.x >> 6);
    int lane = threadIdx.x & 63;
    int k    = cnt[code];
    int off  = offset[code];

    float acc = 0.0f;
    for (int i = 0; i < k; ++i) {
        int row = sorted[off + i];
        float xv = x[(size_t)row * D + lane];
        float ss = xv * xv;
        #pragma unroll
        for (int o = 32; o > 0; o >>= 1) ss += __shfl_xor(ss, o);
        acc += xv * (1.0f / fmaxf(sqrtf(ss), 1e-12f));
    }

    float bsum = (float)k;
    if (lane == 0)
        new_cs_out[code] = cluster_size[code] * DECAY + bsum * (1.0f - DECAY);

    float en;
    if (k == 0) {
        en = embed_n[code * D + lane];
    } else {
        float v = acc / bsum;
        float ss = v * v;
        #pragma unroll
        for (int o = 32; o > 0; o >>= 1) ss += __shfl_xor(ss, o);
        en = v / fmaxf(sqrtf(ss), 1e-12f);
    }
    new_embed_out[code * D + lane] =
        embed[code * D + lane] * DECAY + en * (1.0f - DECAY);
}

// ---------------------------------------------------------------------------
extern "C" void kernel_launch(void* const* d_in, const int* in_sizes, int n_in,
                              void* d_out, int out_size, void* d_ws, size_t ws_size,
                              hipStream_t stream)
{
    const float* x            = (const float*)d_in[0];
    const float* embed        = (const float*)d_in[1];
    const float* cluster_size = (const float*)d_in[2];

    float* out     = (float*)d_out;
    float* q_out   = out;                          // N*D
    float* ind_out = out + (size_t)N * D;          // N
    float* ne_out  = ind_out + N;                  // C*D
    float* ncs_out = ne_out + (size_t)C * D;       // C

    // ws layout (bytes):
    //   embed_n     @ 0          (1 MB)
    //   e_hi        @ 1 MB       (512 KB)
    //   e_lo        @ 1.5 MB     (512 KB)
    //   cnt         @ 2 MB       (16 KB)
    //   offset      @ 2 MB+16K   (16 KB)
    //   slot_arr    @ 2 MB+32K   (256 KB)
    //   sorted      @ 2 MB+288K  (256 KB)
    //   dirty_list  @ 2 MB+544K  (256 KB)
    //   dirty_count @ 2 MB+800K  (4 B)
    char* ws = (char*)d_ws;
    float*          embed_n     = (float*)ws;
    unsigned short* e_hi        = (unsigned short*)(ws + (1u << 20));
    unsigned short* e_lo        = (unsigned short*)(ws + (1u << 20) + 524288);
    int*            cnt         = (int*)(ws + (2u << 20));
    int*            offset      = (int*)(ws + (2u << 20) + 16384);
    int*            slot_arr    = (int*)(ws + (2u << 20) + 32768);
    int*            sorted      = (int*)(ws + (2u << 20) + 32768 + 262144);
    int*            dirty_list  = (int*)(ws + (2u << 20) + 32768 + 524288);
    int*            dirty_count = (int*)(ws + (2u << 20) + 32768 + 786432);

    prep_e_kernel<<<C / 4, 256, 0, stream>>>(embed, embed_n, e_hi, e_lo,
                                             cnt, dirty_count);
    assign_mfma_kernel<<<dim3(N / 256, NCHUNK), 512, 0, stream>>>(
        x, e_hi, e_lo, q_out);
    merge_rescan_kernel<<<N / 4, 256, 0, stream>>>(x, embed, embed_n,
                                                   q_out, ind_out, cnt,
                                                   slot_arr, dirty_count,
                                                   dirty_list);
    fallback_kernel<<<1024, 256, 0, stream>>>(x, embed, embed_n, dirty_count,
                                              dirty_list, ind_out, q_out,
                                              cnt, slot_arr);
    scan_kernel<<<1, 256, 0, stream>>>(cnt, offset);
    scatter_rows_kernel<<<N / 256, 256, 0, stream>>>(ind_out, slot_arr,
                                                     offset, sorted);
    sumfin_kernel<<<C / 4, 256, 0, stream>>>(x, embed, cluster_size, embed_n,
                                             cnt, offset, sorted,
                                             ne_out, ncs_out);
}

// Round 14
// 174.915 us; speedup vs baseline: 1.1445x; 1.1445x over previous
//
#include <hip/hip_runtime.h>
#include <math.h>

#define DECAY 0.8f
constexpr int B_     = 16;
constexpr int NSEQ   = 4096;
constexpr int D      = 64;
constexpr int C      = 4096;
constexpr int N      = B_ * NSEQ;       // 65536 rows
constexpr int NCHUNK = 4;               // code chunks (blockIdx.y)
constexpr int CCHUNK = C / NCHUNK;      // 1024 codes
constexpr int PANEL  = 128;             // codes per panel (32 KB LDS)
constexpr int NPANEL = CCHUNK / PANEL;  // 8
constexpr int TILE_ELEMS = 32 * D;      // 2048 elems per 32-code tile image

#define GATE_THR  3e-4f                  // > 2x mfma-split err (~1e-4 bound)

typedef __attribute__((ext_vector_type(8)))  short bf16x8;
typedef __attribute__((ext_vector_type(16))) float f32x16;

__device__ __forceinline__ unsigned short bf16_rn(float f) {
    unsigned u = __builtin_bit_cast(unsigned, f);
    u += 0x7FFFu + ((u >> 16) & 1u);
    return (unsigned short)(u >> 16);
}
__device__ __forceinline__ float bf16_to_f(unsigned short h) {
    unsigned u = ((unsigned)h) << 16;
    return __builtin_bit_cast(float, u);
}
__device__ __forceinline__ f32x16 mfma32(bf16x8 a, bf16x8 b, f32x16 c) {
    return __builtin_amdgcn_mfma_f32_32x32x16_bf16(a, b, c, 0, 0, 0);
}
__device__ __forceinline__ void gload_lds16(const unsigned short* g,
                                            unsigned short* l) {
    __builtin_amdgcn_global_load_lds(
        (const __attribute__((address_space(1))) unsigned int*)g,
        (__attribute__((address_space(3))) unsigned int*)l, 16, 0, 0);
}

// ---------------------------------------------------------------------------
// Kernel 1: embed_n = l2norm(embed) (f32), bf16 hi/lo split in the
// TRANSPOSED-GRANULE tile image (t*2048 + (g*32+r)*8 + e). Zeroes ncpy
// copies of embed_sum/bins + dirty_count.
// ---------------------------------------------------------------------------
__global__ __launch_bounds__(256) void prep_e_kernel(
    const float* __restrict__ embed,
    float* __restrict__ embed_n,
    unsigned short* __restrict__ e_hi,
    unsigned short* __restrict__ e_lo,
    float* __restrict__ embed_sum,
    float* __restrict__ bins,
    int* __restrict__ dirty_count,
    int ncpy)
{
    int code = blockIdx.x * 4 + (threadIdx.x >> 6);
    int lane = threadIdx.x & 63;
    float v = embed[code * D + lane];
    float ss = v * v;
    #pragma unroll
    for (int o = 32; o > 0; o >>= 1) ss += __shfl_xor(ss, o);
    float inv = 1.0f / fmaxf(sqrtf(ss), 1e-12f);
    float en = v * inv;
    embed_n[code * D + lane] = en;

    unsigned short hi = bf16_rn(en);
    unsigned short lo = bf16_rn(en - bf16_to_f(hi));
    int t = code >> 5, r = code & 31;
    int g = lane >> 3, e = lane & 7;
    size_t pos = (size_t)t * TILE_ELEMS + (g * 32 + r) * 8 + e;
    e_hi[pos] = hi;
    e_lo[pos] = lo;

    for (int k = 0; k < ncpy; ++k) {
        embed_sum[(size_t)k * C * D + code * D + lane] = 0.0f;
        if (lane == 0) bins[k * C + code] = 0.0f;
    }
    if (blockIdx.x == 0 && threadIdx.x == 0) *dirty_count = 0;
}

// ---------------------------------------------------------------------------
// Kernel 2: MFMA partial argmax over a 1024-code chunk (blockIdx.y of 4).
// 512-thread blocks, PANEL=128 (32 KB LDS), 1024 blocks = 4 blocks/CU x 8
// waves = 32 waves/CU. Two independent 6-MFMA chains (ILP).
// EXACT ELEMENTWISE top-2 + index (round-7 semantics, no rescan needed):
// each lane holds 16 of its row's 32 tile-codes; in-tile index cit(r) =
// (r&3)+8*(r>>2) is an INLINE CONSTANT per unrolled r (cndmask src), tile id
// pt is SGPR -> 6 VALU/elem, no index-register array (VGPR stays < 64).
// Exact ties make m2==m1 -> dirty -> fallback (first-max preserved).
// Partial (m1, exact code, exact m2, 0) -> row's quantize slot (f4 @chunk*4).
// ---------------------------------------------------------------------------
__global__ __launch_bounds__(512) void assign_mfma_kernel(
    const float* __restrict__ x,
    const unsigned short* __restrict__ e_hi,
    const unsigned short* __restrict__ e_lo,
    float* __restrict__ part)               // == q_out region of d_out
{
    __shared__ unsigned short lds_hi[4 * TILE_ELEMS];   // 16 KB
    __shared__ unsigned short lds_lo[4 * TILE_ELEMS];   // 16 KB

    const int tid  = threadIdx.x;
    const int lane = tid & 63;
    const int wid  = tid >> 6;                   // 0..7
    const int m    = lane & 31;
    const int hi   = lane >> 5;                  // 0/1
    const int rb   = (blockIdx.x * 8 + wid) * 32;
    const int cy   = blockIdx.y;                 // code chunk 0..3

    // ---- x fragments: 4 K-chunks of 16, bf16 hi/lo split
    bf16x8 xhi[4], xlo[4];
    #pragma unroll
    for (int c = 0; c < 4; ++c) {
        const float* p = x + (size_t)(rb + m) * D + c * 16 + hi * 8;
        float4 t0 = *(const float4*)p;
        float4 t1 = *(const float4*)(p + 4);
        float e[8] = {t0.x, t0.y, t0.z, t0.w, t1.x, t1.y, t1.z, t1.w};
        bf16x8 h, l2;
        #pragma unroll
        for (int j = 0; j < 8; ++j) {
            unsigned short hh = bf16_rn(e[j]);
            h[j]  = (short)hh;
            l2[j] = (short)bf16_rn(e[j] - bf16_to_f(hh));
        }
        xhi[c] = h;
        xlo[c] = l2;
    }

    float m1 = -3.4e38f, m2 = -3.4e38f;
    int   tl = 0, il = 0;

    for (int p = 0; p < NPANEL; ++p) {           // 8 panels of 128 codes
        const size_t pbase = ((size_t)cy * NPANEL + p) * (4 * TILE_ELEMS);
        __syncthreads();
        gload_lds16(e_hi + pbase + tid * 8,        &lds_hi[tid * 8]);
        gload_lds16(e_hi + pbase + 4096 + tid * 8, &lds_hi[4096 + tid * 8]);
        gload_lds16(e_lo + pbase + tid * 8,        &lds_lo[tid * 8]);
        gload_lds16(e_lo + pbase + 4096 + tid * 8, &lds_lo[4096 + tid * 8]);
        __syncthreads();

        #pragma unroll
        for (int t = 0; t < 4; ++t) {            // 4 code-tiles of 32
            const int pt = (cy * NPANEL + p) * 4 + t;    // tile id 0..127
            f32x16 accA = {}, accB = {};         // two independent chains
            #pragma unroll
            for (int c = 0; c < 2; ++c) {
                const int off = t * TILE_ELEMS + ((c * 2 + hi) * 32 + m) * 8;
                bf16x8 eh = *(const bf16x8*)(lds_hi + off);
                bf16x8 el = *(const bf16x8*)(lds_lo + off);
                accA = mfma32(eh, xhi[c], accA);
                accA = mfma32(el, xhi[c], accA);
                accA = mfma32(eh, xlo[c], accA);
            }
            #pragma unroll
            for (int c = 2; c < 4; ++c) {
                const int off = t * TILE_ELEMS + ((c * 2 + hi) * 32 + m) * 8;
                bf16x8 eh = *(const bf16x8*)(lds_hi + off);
                bf16x8 el = *(const bf16x8*)(lds_lo + off);
                accB = mfma32(eh, xhi[c], accB);
                accB = mfma32(el, xhi[c], accB);
                accB = mfma32(eh, xlo[c], accB);
            }
            // exact elementwise top-2 + index over this lane's 16 codes
            // (cit ascending within lane -> strict '>' keeps lowest code)
            #pragma unroll
            for (int r = 0; r < 16; ++r) {
                float v = accA[r] + accB[r];
                const int cit = (r & 3) + 8 * (r >> 2);  // inline const
                bool gt = v > m1;
                float mx = fmaxf(m2, v);
                m2 = gt ? m1 : mx;
                tl = gt ? pt : tl;               // SGPR source
                il = gt ? cit : il;              // inline-const source
                m1 = fmaxf(m1, v);
            }
        }
    }

    // ---- global code; merge the two hi-halves (disjoint code subsets)
    int code = (tl << 5) + il + (hi << 2);
    {
        float b1 = __shfl_xor(m1, 32);
        float b2 = __shfl_xor(m2, 32);
        int   bc = __shfl_xor(code, 32);
        float nm2 = fmaxf(fmaxf(m2, b2), fminf(m1, b1));
        bool  take = (b1 > m1) || (b1 == m1 && bc < code);
        m1   = take ? b1 : m1;
        code = take ? bc : code;
        m2   = nm2;
    }
    if (lane < 32) {
        int row = rb + lane;
        float4 pr;
        pr.x = m1; pr.y = (float)code; pr.z = m2; pr.w = 0.0f;
        *reinterpret_cast<float4*>(part + (size_t)row * D + cy * 4) = pr;
    }
}

// ---------------------------------------------------------------------------
// Kernel 3: merge + scatter, one WAVE per row. NO rescan (assign's indices
// and m2 are exact): winner = compare of 4 chunk partials; gate m1-m2x <=
// GATE_THR (airtight: exact flip needs approx margin <= 2*err < GATE; exact
// ties -> m2==m1 -> dirty). Clean rows: ind + bins + q gather + embed_sum
// atomics (privatized ncpy-ways). Dirty -> fallback.
// ---------------------------------------------------------------------------
__global__ __launch_bounds__(256) void merge_scatter_kernel(
    const float* __restrict__ x,
    const float* __restrict__ embed,
    float* __restrict__ q_out,               // holds partials on entry
    float* __restrict__ ind_out,
    float* __restrict__ embed_sum,
    float* __restrict__ bins,
    int* __restrict__ dirty_count,
    int* __restrict__ dirty_list,
    int ncpy)
{
    int wid  = threadIdx.x >> 6;
    int lane = threadIdx.x & 63;
    int row  = blockIdx.x * 4 + wid;
    int cpy  = blockIdx.x & (ncpy - 1);

    // ---- merge the 4 chunk partials (broadcast reads; chunks ascending)
    float w1, m2x; int wc;
    {
        const float4* pp = reinterpret_cast<const float4*>(q_out + (size_t)row * D);
        float4 P = pp[0];
        w1 = P.x; wc = (int)P.y; m2x = P.z;
        #pragma unroll
        for (int j = 1; j < NCHUNK; ++j) {
            float4 Q = pp[j];
            float nm2 = fmaxf(fmaxf(m2x, Q.z), fminf(w1, Q.x));
            if (Q.x > w1) { w1 = Q.x; wc = (int)Q.y; }
            m2x = nm2;
        }
    }

    bool dirty = (w1 - m2x <= GATE_THR);
    if (dirty) {
        if (lane == 0) {
            int slot = atomicAdd(dirty_count, 1);
            dirty_list[slot] = row;
        }
        return;
    }

    // ---- scatter (clean row)
    float xk = x[(size_t)row * D + lane];
    float ss = xk * xk;
    #pragma unroll
    for (int o = 32; o > 0; o >>= 1) ss += __shfl_xor(ss, o);
    float inv = 1.0f / fmaxf(sqrtf(ss), 1e-12f);

    if (lane == 0) {
        ind_out[row] = (float)wc;
        atomicAdd(&bins[cpy * C + wc], 1.0f);
    }
    q_out[(size_t)row * D + lane] = embed[(size_t)wc * D + lane];
    atomicAdd(&embed_sum[(size_t)cpy * C * D + (size_t)wc * D + lane], xk * inv);
}

// ---------------------------------------------------------------------------
// Kernel 4: exact fp32 re-argmax for dirty rows + their deferred scatter.
// (verified, unchanged semantics)
// ---------------------------------------------------------------------------
__global__ __launch_bounds__(256) void fallback_kernel(
    const float* __restrict__ x,
    const float* __restrict__ embed,
    const float* __restrict__ embed_n,
    const int* __restrict__ dirty_count,
    const int* __restrict__ dirty_list,
    float* __restrict__ ind_out,
    float* __restrict__ q_out,
    float* __restrict__ embed_sum,
    float* __restrict__ bins,
    int ncpy)
{
    __shared__ float xs[D];
    __shared__ float bv[256];
    __shared__ int   bidx[256];
    int cnt = *dirty_count;
    int cpy = blockIdx.x & (ncpy - 1);
    for (int i = blockIdx.x; i < cnt; i += gridDim.x) {
        int row = dirty_list[i];
        __syncthreads();
        if (threadIdx.x < D) xs[threadIdx.x] = x[(size_t)row * D + threadIdx.x];
        __syncthreads();
        float best = -3.4e38f;
        int   bi   = 0;
        int   c0   = threadIdx.x * 16;
        for (int c = c0; c < c0 + 16; ++c) {
            const float4* ep = (const float4*)(embed_n + (size_t)c * D);
            const float4* xp = (const float4*)xs;
            float a0 = 0.f, a1 = 0.f, a2 = 0.f, a3 = 0.f;
            #pragma unroll
            for (int k = 0; k < D / 4; ++k) {
                float4 e = ep[k], xx = xp[k];
                a0 = fmaf(e.x, xx.x, a0);
                a1 = fmaf(e.y, xx.y, a1);
                a2 = fmaf(e.z, xx.z, a2);
                a3 = fmaf(e.w, xx.w, a3);
            }
            float dd = (a0 + a1) + (a2 + a3);
            if (dd > best) { best = dd; bi = c; }
        }
        bv[threadIdx.x]   = best;
        bidx[threadIdx.x] = bi;
        __syncthreads();
        #pragma unroll
        for (int s = 128; s > 0; s >>= 1) {
            if (threadIdx.x < s) {
                float v2 = bv[threadIdx.x + s];
                int   i2 = bidx[threadIdx.x + s];
                if (v2 > bv[threadIdx.x] ||
                    (v2 == bv[threadIdx.x] && i2 < bidx[threadIdx.x])) {
                    bv[threadIdx.x]   = v2;
                    bidx[threadIdx.x] = i2;
                }
            }
            __syncthreads();
        }
        int fi = bidx[0];
        if (threadIdx.x == 0) {
            ind_out[row] = (float)fi;
            atomicAdd(&bins[cpy * C + fi], 1.0f);
        }
        if (threadIdx.x < 64) {
            float xk = xs[threadIdx.x];
            float ss = xk * xk;
            #pragma unroll
            for (int o = 32; o > 0; o >>= 1) ss += __shfl_xor(ss, o);
            float inv = 1.0f / fmaxf(sqrtf(ss), 1e-12f);
            q_out[(size_t)row * D + threadIdx.x] =
                embed[(size_t)fi * D + threadIdx.x];
            atomicAdd(&embed_sum[(size_t)cpy * C * D + (size_t)fi * D + threadIdx.x],
                      xk * inv);
        }
        __syncthreads();
    }
}

// ---------------------------------------------------------------------------
// Kernel 5: EMA finalize per code. One wave per code; sums the ncpy
// privatized copies of bins/embed_sum first.
// ---------------------------------------------------------------------------
__global__ __launch_bounds__(256) void finalize_kernel(
    const float* __restrict__ embed,
    const float* __restrict__ cluster_size,
    const float* __restrict__ embed_n,
    const float* __restrict__ embed_sum,
    const float* __restrict__ bins,
    float* __restrict__ new_embed_out,
    float* __restrict__ new_cs_out,
    int ncpy)
{
    int code = blockIdx.x * 4 + (threadIdx.x >> 6);
    int lane = threadIdx.x & 63;
    float bsum = 0.0f;
    for (int k = 0; k < ncpy; ++k) bsum += bins[k * C + code];
    if (lane == 0)
        new_cs_out[code] = cluster_size[code] * DECAY + bsum * (1.0f - DECAY);

    float en;
    if (bsum == 0.0f) {
        en = embed_n[code * D + lane];
    } else {
        float vsum = 0.0f;
        for (int k = 0; k < ncpy; ++k)
            vsum += embed_sum[(size_t)k * C * D + code * D + lane];
        float v = vsum / bsum;
        float ss = v * v;
        #pragma unroll
        for (int o = 32; o > 0; o >>= 1) ss += __shfl_xor(ss, o);
        en = v / fmaxf(sqrtf(ss), 1e-12f);
    }
    new_embed_out[code * D + lane] =
        embed[code * D + lane] * DECAY + en * (1.0f - DECAY);
}

// ---------------------------------------------------------------------------
extern "C" void kernel_launch(void* const* d_in, const int* in_sizes, int n_in,
                              void* d_out, int out_size, void* d_ws, size_t ws_size,
                              hipStream_t stream)
{
    const float* x            = (const float*)d_in[0];
    const float* embed        = (const float*)d_in[1];
    const float* cluster_size = (const float*)d_in[2];

    float* out     = (float*)d_out;
    float* q_out   = out;                          // N*D
    float* ind_out = out + (size_t)N * D;          // N
    float* ne_out  = ind_out + N;                  // C*D
    float* ncs_out = ne_out + (size_t)C * D;       // C

    // ws layout (bytes):
    //   embed_n     @ 0        (1 MB)
    //   e_hi        @ 1 MB     (512 KB)
    //   e_lo        @ 1.5 MB   (512 KB)
    //   bins        @ 2 MB     (ncpy * 16 KB, ncpy<=4)
    //   dirty_list  @ 2.25 MB  (256 KB)
    //   dirty_count @ 2.5 MB   (4 B)
    //   embed_sum   @ 3 MB     (ncpy * 1 MB)
    char* ws = (char*)d_ws;
    float*          embed_n     = (float*)ws;
    unsigned short* e_hi        = (unsigned short*)(ws + (1u << 20));
    unsigned short* e_lo        = (unsigned short*)(ws + (1u << 20) + 524288);
    float*          bins        = (float*)(ws + (2u << 20));
    int*            dirty_list  = (int*)(ws + (2u << 20) + 262144);
    int*            dirty_count = (int*)(ws + (2u << 20) + 524288);
    float*          embed_sum   = (float*)(ws + (3u << 20));

    const size_t need4 = (3u << 20) + 4u * ((size_t)C * D * 4);
    const int ncpy = (ws_size >= need4) ? 4 : 1;   // privatization degree

    prep_e_kernel<<<C / 4, 256, 0, stream>>>(embed, embed_n, e_hi, e_lo,
                                             embed_sum, bins, dirty_count, ncpy);
    assign_mfma_kernel<<<dim3(N / 256, NCHUNK), 512, 0, stream>>>(
        x, e_hi, e_lo, q_out);
    merge_scatter_kernel<<<N / 4, 256, 0, stream>>>(x, embed, q_out, ind_out,
                                                    embed_sum, bins,
                                                    dirty_count, dirty_list, ncpy);
    fallback_kernel<<<1024, 256, 0, stream>>>(x, embed, embed_n, dirty_count,
                                              dirty_list, ind_out, q_out,
                                              embed_sum, bins, ncpy);
    finalize_kernel<<<C / 4, 256, 0, stream>>>(embed, cluster_size, embed_n,
                                               embed_sum, bins, ne_out, ncs_out,
                                               ncpy);
}